// Round 8
// baseline (296.600 us; speedup 1.0000x reference)
//
#include <hip/hip_runtime.h>
#include <math.h>

// ---------------------------------------------------------------------------
// PredictiveModule R8: single persistent kernel, R6's proven pipeline inside.
//
// 256 blocks x 512 threads (8 waves/CU, 1 block/CU, 133KB LDS), 4 device
// barriers. Matvec phases use the R6 TR=8 wave-private global_load_lds
// double-buffer: stage 8 rows (8KB), loop { stage next tile, vmcnt(8),
// consume 8 rows via float4 LDS reads + f64 FMA }. No __syncthreads in the
// K-loop => no compiler vmcnt(0) drain; in-flight = 8KB/wave * 8 waves.
//
// Phases:
//   P1 mv1: units (bx in 2, by in 128), KC=128: p1[128][4096]
//   P2 mv2: prologue-reduce(p1,+b1,relu) -> xs; KC=32: p2[128][4096]
//   P3 mv3: prologue-reduce(p2,+b2,relu) -> xs; KC=128, N=D: p3[32][16384]
//   P4 finalize: reduce p3 + gate/clip/sample + lpp[256]
//   P5 topk (block 0): radix-select, stable ties by index, write out+logprob
//
// Numerics: f64 accumulation (HBM-bound; f64 free); f32 rounding only at
// sample = f32(am) + 0.05f*noise. absmax must stay 0.
// ---------------------------------------------------------------------------

constexpr int D  = 16384;
constexpr int H  = 4096;
constexpr int NB = 256;        // blocks (1 per CU)
constexpr int T  = 512;        // threads (8 waves)
constexpr int TR = 8;          // rows per pipeline tile

constexpr int KC1 = 128, KC2 = 32, KC3 = 128;
constexpr int G1 = D / KC1;    // 128
constexpr int G2 = H / KC2;    // 128
constexpr int G3 = H / KC3;    // 32

__device__ __forceinline__ void stage16(const float* g, const float* l) {
    __builtin_amdgcn_global_load_lds(
        (const __attribute__((address_space(1))) unsigned int*)g,
        (__attribute__((address_space(3))) unsigned int*)l,
        16, 0, 0);
}

__device__ __forceinline__ double wredsum(double v) {
    #pragma unroll
    for (int o = 32; o > 0; o >>= 1) v += __shfl_down(v, o, 64);
    return v;
}

__device__ __forceinline__ void gbar(int* bar, int phase) {
    __syncthreads();
    if (threadIdx.x == 0) {
        __threadfence();
        if (atomicAdd(&bar[phase], 1) == NB - 1)
            atomicAdd(&bar[15], 1);   // generation cell: monotonic
        while (__hip_atomic_load(&bar[15], __ATOMIC_ACQUIRE,
                                 __HIP_MEMORY_SCOPE_AGENT) < phase + 1)
            __builtin_amdgcn_s_sleep(2);
        __threadfence();
    }
    __syncthreads();
}

struct SM {
    union {
        struct {
            float wbuf[8][2][TR][256];   // 128 KB wave-private double buffers
            double xs[KC1];              // 1 KB
            double xred[T];              // 4 KB
        } mv;
        struct {
            unsigned int u[D];           // 64 KB
            int whist[8][257];
            int hist[256]; int sfx[256];
            int wsum[8]; int wcnt[4];
            unsigned int s_prefix; int s_kk;
        } tk;
    };
};

// One split-K matvec phase. Block covers cols [bx*2048,+2048), rows [by*KC,+KC).
template<int KC, bool FRED, int N, int K, int XC, int GPREV>
__device__ __forceinline__ void mv_phase(
    const float* __restrict__ W,
    const float* __restrict__ xf,        // !FRED: raw f32 x
    const double* __restrict__ xpart,    // FRED: prev partials [GPREV][K]
    const float* __restrict__ bias,
    double* __restrict__ ypart,          // [K/KC][N]
    int u, int t, SM& sm)
{
    const int lane = t & 63, w = t >> 6;
    const int bx = u % XC, by = u / XC;
    const int k0 = by * KC;

    if constexpr (!FRED) {
        if (t < KC) sm.mv.xs[t] = (double)xf[k0 + t];
    } else {
        constexpr int NS = T / KC;       // slices over GPREV
        const int kl = t & (KC - 1), sl = t / KC;
        double s = 0.0;
        #pragma unroll
        for (int g = sl; g < GPREV; g += NS)
            s += xpart[(size_t)g * K + k0 + kl];
        sm.mv.xred[t] = s;
        __syncthreads();
        if (t < KC) {
            double tot = (double)bias[k0 + t];
            #pragma unroll
            for (int s2 = 0; s2 < NS; ++s2) tot += sm.mv.xred[s2 * KC + t];
            sm.mv.xs[t] = tot > 0.0 ? tot : 0.0;     // relu
        }
    }
    __syncthreads();

    const int cbase = bx * 2048 + w * 256;
    const float* Wg = W + (size_t)k0 * N + cbase + lane * 4;
    float* b0 = &sm.mv.wbuf[w][0][0][0];
    float* b1 = &sm.mv.wbuf[w][1][0][0];

    #pragma unroll
    for (int r = 0; r < TR; ++r)                     // stage tile 0
        stage16(Wg + (size_t)r * N, b0 + r * 256);

    double a0 = 0, a1 = 0, a2 = 0, a3 = 0;
    constexpr int TILES = KC / TR;
    for (int tt = 0; tt < TILES; ++tt) {
        if (tt + 1 < TILES) {
            const float* Wn = Wg + (size_t)(tt + 1) * TR * N;
            #pragma unroll
            for (int r = 0; r < TR; ++r)             // stage tile tt+1
                stage16(Wn + (size_t)r * N, b1 + r * 256);
            asm volatile("s_waitcnt vmcnt(8)" ::: "memory");  // tile tt landed
        } else {
            asm volatile("s_waitcnt vmcnt(0)" ::: "memory");
        }
        #pragma unroll
        for (int r = 0; r < TR; ++r) {               // consume tile tt
            const float4 wv = *reinterpret_cast<const float4*>(b0 + r * 256 + lane * 4);
            const double x = sm.mv.xs[tt * TR + r];
            a0 += x * (double)wv.x; a1 += x * (double)wv.y;
            a2 += x * (double)wv.z; a3 += x * (double)wv.w;
        }
        float* tmp = b0; b0 = b1; b1 = tmp;
    }

    double* yp = ypart + (size_t)by * N + cbase + lane * 4;
    *reinterpret_cast<double2*>(yp + 0) = make_double2(a0, a1);
    *reinterpret_cast<double2*>(yp + 2) = make_double2(a2, a3);
}

__global__ __launch_bounds__(T, 2) void k_fused(
    const float* __restrict__ ct,  const float* __restrict__ W1,
    const float* __restrict__ b1,  const float* __restrict__ W2,
    const float* __restrict__ b2,  const float* __restrict__ W3,
    const float* __restrict__ b3,  const float* __restrict__ qm,
    const float* __restrict__ noise, const int* __restrict__ kptr,
    int* bar, double* p1, double* p2, double* p3,
    float* samp, double* lpp, float* out)
{
    __shared__ SM sm;
    const int b = blockIdx.x, t = threadIdx.x;
    const int lane = t & 63, wid = t >> 6;

    // P1: mv1  (K=D, N=H)
    mv_phase<KC1, false, H, D, 2, 0>(W1, ct, nullptr, nullptr, p1, b, t, sm);
    gbar(bar, 0);
    // P2: mv2  (K=H, N=H), x = relu(reduce(p1)+b1)
    mv_phase<KC2, true, H, H, 2, G1>(W2, nullptr, p1, b1, p2, b, t, sm);
    gbar(bar, 1);
    // P3: mv3  (K=H, N=D), x = relu(reduce(p2)+b2)
    mv_phase<KC3, true, D, H, 8, G2>(W3, nullptr, p2, b2, p3, b, t, sm);
    gbar(bar, 2);

    // P4: finalize — 64 cols per block
    {
        const int c0 = b * (D / NB);
        const int cl = t & 63, gs = t >> 6;          // 8 slices over G3=32
        double s = 0.0;
        #pragma unroll
        for (int g = gs; g < G3; g += 8)             // 4 iters
            s += p3[(size_t)g * D + c0 + cl];
        sm.mv.xred[gs * 64 + cl] = s;
        __syncthreads();
        if (t < 64) {
            const int c = c0 + t;
            double vm = (double)b3[c];
            #pragma unroll
            for (int s2 = 0; s2 < 8; ++s2) vm += sm.mv.xred[s2 * 64 + t];
            vm = vm > 100.0 ? 100.0 : (vm < -100.0 ? -100.0 : vm);
            const double z = (double)qm[c] * (double)ct[c];
            const double g = 1.0 / (1.0 + exp(-z));
            double am = g * vm;                      // influence == 1.0
            am = am > 1000.0 ? 1000.0 : (am < -1000.0 ? -1000.0 : am);
            const float amf = (float)am;
            const float sp = amf + 0.05f * noise[c];
            samp[c] = sp;
            const float df = (sp - amf) / 0.05f;
            double term = (double)df * (double)df;
            term = wredsum(term);                    // t<64 == wave 0
            if (t == 0) lpp[b] = term;
        }
    }
    gbar(bar, 3);

    // P5: block 0 only — radix-select top-k + final writes
    if (b != 0) return;

    for (int i = t; i < D; i += T)
        sm.tk.u[i] = __float_as_uint(samp[i]) & 0x7fffffffu;
    __syncthreads();

    const int k = *kptr;
    unsigned int prefix = 0;
    int kk = k;
    for (int pass = 0; pass < 4; ++pass) {
        const int shift = 24 - 8 * pass;
        const unsigned int dm = pass ? (0xffffffffu << (32 - 8 * pass)) : 0u;
        for (int i = t; i < 8 * 257; i += T) (&sm.tk.whist[0][0])[i] = 0;
        __syncthreads();
        for (int i = t; i < D; i += T) {
            const unsigned int v = sm.tk.u[i];
            if ((v & dm) == prefix)
                atomicAdd(&sm.tk.whist[wid][(v >> shift) & 0xff], 1);
        }
        __syncthreads();
        if (t < 256) {
            int s = 0;
            #pragma unroll
            for (int w = 0; w < 8; ++w) s += sm.tk.whist[w][t];
            sm.tk.hist[t] = s;
            sm.tk.sfx[t] = s;
        }
        __syncthreads();
        #pragma unroll
        for (int off = 1; off < 256; off <<= 1) {
            int add = 0;
            if (t < 256 && t + off < 256) add = sm.tk.sfx[t + off];
            __syncthreads();
            if (t < 256) sm.tk.sfx[t] += add;
            __syncthreads();
        }
        const bool cond = (t < 256) && (sm.tk.sfx[t] >= kk);
        const unsigned long long m = __ballot(cond);
        if (lane == 0 && wid < 4) sm.tk.wcnt[wid] = __popcll(m);
        __syncthreads();
        if (t == 0) {
            const int bs = sm.tk.wcnt[0] + sm.tk.wcnt[1] + sm.tk.wcnt[2] + sm.tk.wcnt[3] - 1;
            sm.tk.s_kk = kk - (sm.tk.sfx[bs] - sm.tk.hist[bs]);
            sm.tk.s_prefix = prefix | ((unsigned int)bs << shift);
        }
        __syncthreads();
        prefix = sm.tk.s_prefix;
        kk = sm.tk.s_kk;
        __syncthreads();
    }
    const unsigned int vstar = prefix;
    const int need = kk;   // ties (lowest index) to keep

    // stable tie-rank: contiguous per-thread chunks preserve index order
    constexpr int PER = D / T;  // 32
    const int base = t * PER;
    int cnt = 0;
    #pragma unroll
    for (int j = 0; j < PER; ++j)
        cnt += (sm.tk.u[base + j] == vstar) ? 1 : 0;
    int inc = cnt;
    #pragma unroll
    for (int o = 1; o < 64; o <<= 1) {
        const int n = __shfl_up(inc, o, 64);
        if (lane >= o) inc += n;
    }
    if (lane == 63) sm.tk.wsum[wid] = inc;
    __syncthreads();
    int woff = 0;
    for (int w = 0; w < wid; ++w) woff += sm.tk.wsum[w];
    int offset = woff + inc - cnt;
    #pragma unroll
    for (int j = 0; j < PER; ++j) {
        const int i = base + j;
        const unsigned int v = sm.tk.u[i];
        float o2 = 0.0f;
        if (v > vstar) {
            o2 = samp[i];
        } else if (v == vstar) {
            if (offset < need) o2 = samp[i];
            offset++;
        }
        out[i] = o2;
    }

    if (wid == 0) {                                  // logprob
        double s = 0;
        for (int g = lane; g < NB; g += 64) s += lpp[g];
        s = wredsum(s);
        if (lane == 0) {
            const double c = -log(0.05) - 0.5 * log(2.0 * 3.14159265358979323846);
            out[D] = (float)(-0.5 * s + (double)D * c);
        }
    }
}

extern "C" void kernel_launch(void* const* d_in, const int* in_sizes, int n_in,
                              void* d_out, int out_size, void* d_ws, size_t ws_size,
                              hipStream_t stream) {
    const float* ct    = (const float*)d_in[0];
    const float* W1    = (const float*)d_in[1];
    const float* b1    = (const float*)d_in[2];
    const float* W2    = (const float*)d_in[3];
    const float* b2    = (const float*)d_in[4];
    const float* W3    = (const float*)d_in[5];
    const float* b3    = (const float*)d_in[6];
    const float* qm    = (const float*)d_in[7];
    const float* noise = (const float*)d_in[8];
    const int*   kp    = (const int*)d_in[9];

    // ws: bar(256B) | p1[128][4096] | p2[128][4096] | p3[32][16384] |
    //     samp[D] f32 | lpp[256]
    int*    bar  = (int*)d_ws;
    double* p1   = (double*)((char*)d_ws + 256);
    double* p2   = p1 + (size_t)G1 * H;
    double* p3   = p2 + (size_t)G2 * H;
    float*  samp = (float*)(p3 + (size_t)G3 * D);
    double* lpp  = (double*)(samp + D);

    hipMemsetAsync(d_ws, 0, 256, stream);   // barrier state: deterministic
    k_fused<<<dim3(NB), dim3(T), 0, stream>>>(
        ct, W1, b1, W2, b2, W3, b3, qm, noise, kp,
        bar, p1, p2, p3, samp, lpp, (float*)d_out);
}

// Round 9
// 142.755 us; speedup vs baseline: 2.0777x; 2.0777x over previous
//
#include <hip/hip_runtime.h>
#include <math.h>

// ---------------------------------------------------------------------------
// PredictiveModule R9 = R6 (best, 174.7us) + ReLU row-skip in mv2/mv3.
//
// Persistent/fused designs are abandoned: R4/R5/R8 all ran ~1 TB/s vs the
// same inner loops at 2.5-4x in separate kernels.
//
// Matvec pipeline (R6-proven): 256 thr / 4 waves; wave owns 256 cols; tiles
// of 8 rows x 1KB staged via global_load_lds into wave-private LDS double
// buffers; s_waitcnt vmcnt(8) => tile t landed while t+1 is in flight; no
// __syncthreads in the K-loop.
//
// NEW: mv2/mv3 prologue loads the dense relu'd x (f64, 1KB), ballot-compacts
// nonzero row indices (order-preserving), pads to a multiple of 8, and the
// pipeline stages ONLY those rows. Skipping x==0 rows is bit-exact: each
// skipped row contributes +0.0 to every f64 accumulator, and the remaining
// terms keep their relative order. ~50% of W2/W3 bytes skipped (~160MB).
//
// Numerics: f64 accumulation; f32 rounding only at sample = f32(am)+0.05f*n.
// Top-k: radix-select, ties stable by ascending index (jax.lax.top_k).
// ---------------------------------------------------------------------------

constexpr int D = 16384;
constexpr int H = 4096;

__device__ __forceinline__ void stage16(const float* g, const float* l) {
    __builtin_amdgcn_global_load_lds(
        (const __attribute__((address_space(1))) unsigned int*)g,
        (__attribute__((address_space(3))) unsigned int*)l,
        16, 0, 0);
}

__device__ __forceinline__ double wredsum(double v) {
    #pragma unroll
    for (int o = 32; o > 0; o >>= 1) v += __shfl_down(v, o, 64);
    return v;
}

// Split-K matvec: grid (N/1024, K/KC). Block: 256 thr / 4 waves; wave w owns
// cols [bx*1024 + w*256, +256). SPARSE: compact nonzero rows of xd (relu'd
// dense f64) and stage only those. Writes f64 partials ypart[by][N].
template<int KC, bool SPARSE>
__global__ __launch_bounds__(256) void k_mv(
    const float* __restrict__ W, int N,
    const float* __restrict__ xf,      // !SPARSE: dense f32 x (mv1: ct)
    const double* __restrict__ xd,     // SPARSE: dense f64 relu'd x
    double* __restrict__ ypart)
{
    constexpr int NWC = (KC + 63) / 64;    // waves covering t < KC
    __shared__ float wbuf[4][2][8][256];   // 64 KB wave-private double buffers
    __shared__ double xv[KC];
    __shared__ int cidx[KC];
    __shared__ int wtot[NWC > 0 ? NWC : 1];
    __shared__ int s_nt;

    const int t = threadIdx.x, lane = t & 63, w = t >> 6;
    const int k0 = blockIdx.y * KC;

    if constexpr (!SPARSE) {
        if (t < KC) { xv[t] = (double)xf[k0 + t]; cidx[t] = t; }
        if (t == 0) s_nt = KC / 8;
    } else {
        double x = 0.0; bool pred = false;
        if (t < KC) { x = xd[k0 + t]; pred = x > 0.0; }
        const unsigned long long mask = __ballot(pred);
        const int rank = __popcll(mask & ((1ull << lane) - 1ull));
        const int tot  = __popcll(mask);
        if (t < KC && lane == 0) wtot[t >> 6] = tot;
        __syncthreads();
        int woffs = 0;
        #pragma unroll
        for (int ww = 0; ww < NWC; ++ww)
            if (ww < (t >> 6)) woffs += wtot[ww];
        if (pred) { cidx[woffs + rank] = t; xv[woffs + rank] = x; }
        int m = 0;
        #pragma unroll
        for (int ww = 0; ww < NWC; ++ww) m += wtot[ww];
        const int m8 = (m + 7) & ~7;
        __syncthreads();                    // cidx/xv writes visible
        if (t >= m && t < m8) { cidx[t] = 0; xv[t] = 0.0; }
        if (t == 0) s_nt = m8 / 8;
    }
    __syncthreads();
    const int nt = s_nt;

    const int cbase = blockIdx.x * 1024 + w * 256;
    const float* Wg = W + (size_t)k0 * N + cbase + lane * 4;
    float* b0 = &wbuf[w][0][0][0];
    float* b1 = &wbuf[w][1][0][0];
    double a0 = 0, a1 = 0, a2 = 0, a3 = 0;

    if (nt > 0) {
        #pragma unroll
        for (int r = 0; r < 8; ++r)                     // stage tile 0
            stage16(Wg + (size_t)cidx[r] * N, b0 + r * 256);

        for (int tt = 0; tt < nt; ++tt) {
            if (tt + 1 < nt) {
                const int j = (tt + 1) * 8;
                #pragma unroll
                for (int r = 0; r < 8; ++r)             // stage tile tt+1
                    stage16(Wg + (size_t)cidx[j + r] * N, b1 + r * 256);
                asm volatile("s_waitcnt vmcnt(8)" ::: "memory");  // tt landed
            } else {
                asm volatile("s_waitcnt vmcnt(0)" ::: "memory");
            }
            #pragma unroll
            for (int r = 0; r < 8; ++r) {               // consume tile tt
                const float4 wv = *reinterpret_cast<const float4*>(b0 + r * 256 + lane * 4);
                const double x = xv[tt * 8 + r];
                a0 += x * (double)wv.x; a1 += x * (double)wv.y;
                a2 += x * (double)wv.z; a3 += x * (double)wv.w;
            }
            float* tmp = b0; b0 = b1; b1 = tmp;
        }
    }

    double* yp = ypart + (size_t)blockIdx.y * N + cbase + lane * 4;
    *reinterpret_cast<double2*>(yp + 0) = make_double2(a0, a1);
    *reinterpret_cast<double2*>(yp + 2) = make_double2(a2, a3);
}

// x[j] = relu(bias[j] + sum_g part[g][j]);  grid N/256.
__global__ __launch_bounds__(256) void k_reduce_x(
    const double* __restrict__ part, int G, int N,
    const float* __restrict__ bias, double* __restrict__ xout)
{
    const int j = blockIdx.x * 256 + threadIdx.x;
    double s0 = 0, s1 = 0;
    #pragma unroll 4
    for (int g = 0; g + 1 < G; g += 2) {
        s0 += part[(size_t)g * N + j];
        s1 += part[(size_t)(g + 1) * N + j];
    }
    double s = (double)bias[j] + s0 + s1;
    xout[j] = s > 0.0 ? s : 0.0;
}

// Reduce p3 (G groups) + gate/clip/sample + per-block logprob partial.
__global__ __launch_bounds__(256) void k_finalize(
    const double* __restrict__ p3, int G,
    const float* __restrict__ b3,
    const float* __restrict__ qm,
    const float* __restrict__ ct,
    const float* __restrict__ noise,
    float* __restrict__ samp,
    double* __restrict__ lpp)
{
    const int i = blockIdx.x * 256 + threadIdx.x;
    double s0 = 0, s1 = 0;
    #pragma unroll 4
    for (int g = 0; g + 1 < G; g += 2) {
        s0 += p3[(size_t)g * D + i];
        s1 += p3[(size_t)(g + 1) * D + i];
    }
    double vm = (double)b3[i] + s0 + s1;
    vm = vm > 100.0 ? 100.0 : (vm < -100.0 ? -100.0 : vm);
    const double z = (double)qm[i] * (double)ct[i];
    const double g = 1.0 / (1.0 + exp(-z));
    double am = g * vm;                          // influence == 1.0
    am = am > 1000.0 ? 1000.0 : (am < -1000.0 ? -1000.0 : am);
    const float amf = (float)am;
    const float sp = amf + 0.05f * noise[i];
    samp[i] = sp;
    const float df = (sp - amf) / 0.05f;
    double term = (double)df * (double)df;
    term = wredsum(term);
    __shared__ double red[4];
    const int lane = threadIdx.x & 63, wid = threadIdx.x >> 6;
    if (lane == 0) red[wid] = term;
    __syncthreads();
    if (threadIdx.x == 0) lpp[blockIdx.x] = red[0] + red[1] + red[2] + red[3];
}

// Single-block radix-select top-k (stable ties by index) + final writes.
#define TPK 1024
__global__ __launch_bounds__(TPK) void k_topk(
    const float* __restrict__ samp,
    const int* __restrict__ kptr,
    const double* __restrict__ lpp, int GLP,
    float* __restrict__ out)
{
    __shared__ unsigned int u[16384];
    __shared__ int whist[16][257];
    __shared__ int hist[256];
    __shared__ int sfx[256];
    __shared__ int wsum[16];
    __shared__ int wcnt[4];
    __shared__ unsigned int s_prefix;
    __shared__ int s_kk;

    const int t = threadIdx.x;
    const int lane = t & 63, wid = t >> 6;

    for (int i = t; i < D; i += TPK)
        u[i] = __float_as_uint(samp[i]) & 0x7fffffffu;
    __syncthreads();

    const int k = *kptr;
    unsigned int prefix = 0;
    int kk = k;
    for (int pass = 0; pass < 4; ++pass) {
        const int shift = 24 - 8 * pass;
        const unsigned int dm = pass ? (0xffffffffu << (32 - 8 * pass)) : 0u;
        for (int i = t; i < 16 * 257; i += TPK) (&whist[0][0])[i] = 0;
        __syncthreads();
        for (int i = t; i < D; i += TPK) {
            const unsigned int v = u[i];
            if ((v & dm) == prefix)
                atomicAdd(&whist[wid][(v >> shift) & 0xff], 1);
        }
        __syncthreads();
        if (t < 256) {
            int s = 0;
            #pragma unroll
            for (int w = 0; w < 16; ++w) s += whist[w][t];
            hist[t] = s;
            sfx[t] = s;
        }
        __syncthreads();
        #pragma unroll
        for (int off = 1; off < 256; off <<= 1) {
            int add = 0;
            if (t < 256 && t + off < 256) add = sfx[t + off];
            __syncthreads();
            if (t < 256) sfx[t] += add;
            __syncthreads();
        }
        const bool cond = (t < 256) && (sfx[t] >= kk);
        const unsigned long long m = __ballot(cond);
        if (lane == 0 && wid < 4) wcnt[wid] = __popcll(m);
        __syncthreads();
        if (t == 0) {
            const int bs = wcnt[0] + wcnt[1] + wcnt[2] + wcnt[3] - 1;
            s_kk = kk - (sfx[bs] - hist[bs]);
            s_prefix = prefix | ((unsigned int)bs << shift);
        }
        __syncthreads();
        prefix = s_prefix;
        kk = s_kk;
        __syncthreads();
    }
    const unsigned int vstar = prefix;
    const int need = kk;

    constexpr int PER = D / TPK;  // 16
    const int base = t * PER;
    float vals[PER];
    unsigned int keys[PER];
    int cnt = 0;
    #pragma unroll
    for (int j = 0; j < PER; ++j) {
        const float f = samp[base + j];
        vals[j] = f;
        keys[j] = __float_as_uint(f) & 0x7fffffffu;
        cnt += (keys[j] == vstar) ? 1 : 0;
    }
    int inc = cnt;
    #pragma unroll
    for (int o = 1; o < 64; o <<= 1) {
        const int n = __shfl_up(inc, o, 64);
        if (lane >= o) inc += n;
    }
    if (lane == 63) wsum[wid] = inc;
    __syncthreads();
    int woff = 0;
    for (int w = 0; w < wid; ++w) woff += wsum[w];
    int offset = woff + inc - cnt;
    #pragma unroll
    for (int j = 0; j < PER; ++j) {
        float o2 = 0.0f;
        if (keys[j] > vstar) {
            o2 = vals[j];
        } else if (keys[j] == vstar) {
            if (offset < need) o2 = vals[j];
            offset++;
        }
        out[base + j] = o2;
    }

    if (wid == 0) {
        double s = 0;
        for (int g = lane; g < GLP; g += 64) s += lpp[g];
        s = wredsum(s);
        if (lane == 0) {
            const double c = -log(0.05) - 0.5 * log(2.0 * 3.14159265358979323846);
            out[D] = (float)(-0.5 * s + (double)D * c);
        }
    }
}

extern "C" void kernel_launch(void* const* d_in, const int* in_sizes, int n_in,
                              void* d_out, int out_size, void* d_ws, size_t ws_size,
                              hipStream_t stream) {
    const float* ct    = (const float*)d_in[0];
    const float* W1    = (const float*)d_in[1];
    const float* b1    = (const float*)d_in[2];
    const float* W2    = (const float*)d_in[3];
    const float* b2    = (const float*)d_in[4];
    const float* W3    = (const float*)d_in[5];
    const float* b3    = (const float*)d_in[6];
    const float* qm    = (const float*)d_in[7];
    const float* noise = (const float*)d_in[8];
    const int*   kp    = (const int*)d_in[9];

    // R6 geometry: 512-block matvec grids (2 blocks/CU at ~66KB LDS)
    constexpr int KC1 = 128, KC2 = 32, KC3 = 128;
    constexpr int G1 = D / KC1;   // 128
    constexpr int G2 = H / KC2;   // 128
    constexpr int G3 = H / KC3;   // 32
    constexpr int GLP = D / 256;  // 64

    // ws: p1[128][4096] | p2[128][4096] | p3[32][16384] | x2[H] | x3[H] |
    //     samp[D] f32 | lpp[GLP]
    double* p1   = (double*)d_ws;
    double* p2   = p1 + (size_t)G1 * H;
    double* p3   = p2 + (size_t)G2 * H;
    double* x2   = p3 + (size_t)G3 * D;
    double* x3   = x2 + H;
    float*  samp = (float*)(x3 + H);
    double* lpp  = (double*)(samp + D);

    k_mv<KC1, false><<<dim3(H / 1024, G1), 256, 0, stream>>>(W1, H, ct, nullptr, p1);
    k_reduce_x<<<dim3(H / 256), 256, 0, stream>>>(p1, G1, H, b1, x2);
    k_mv<KC2, true><<<dim3(H / 1024, G2), 256, 0, stream>>>(W2, H, nullptr, x2, p2);
    k_reduce_x<<<dim3(H / 256), 256, 0, stream>>>(p2, G2, H, b2, x3);
    k_mv<KC3, true><<<dim3(D / 1024, G3), 256, 0, stream>>>(W3, D, nullptr, x3, p3);
    k_finalize<<<dim3(D / 256), 256, 0, stream>>>(p3, G3, b3, qm, ct, noise, samp, lpp);
    k_topk<<<dim3(1), TPK, 0, stream>>>(samp, kp, lpp, GLP, (float*)d_out);
}